// Round 7
// baseline (127.661 us; speedup 1.0000x reference)
//
#include <hip/hip_runtime.h>
#include <hip/hip_bf16.h>
#include <cstddef>

#define H_ 128   // hidden/channels/state
#define F_ 128   // freq bins
#define B_ 4     // batch
#define T_ 512   // time
#define TC 64    // time chunk
#define NCH (T_ / TC)

typedef short short8 __attribute__((ext_vector_type(8)));   // 8 bf16 (4 VGPRs)
typedef float f32x4 __attribute__((ext_vector_type(4)));
typedef float f4 __attribute__((ext_vector_type(4)));
typedef unsigned int uint32;

static __device__ __forceinline__ unsigned short f2bf(float x) {
    __hip_bfloat16 h = __float2bfloat16(x);   // RNE
    return __builtin_bit_cast(unsigned short, h);
}

// R7 = R2 numerics/structure EXACTLY (single-buffer staging, 4 syncs/chunk,
// gam post-multiply, kb-outer MFMA order, global fp32 D*x, serial scan),
// widened to 512 threads/block: 8 waves, each wave owns ONE 16-wide n/h tile.
// Same accumulation order per output element -> expect bit-identical to R2.
// dbuf prefetch permanently dropped (R3-R6: nondeterministic failures).
__global__ __launch_bounds__(512, 4)
void lru_mfma7_kernel(const float* __restrict__ x,
                      const float* __restrict__ nu_log,
                      const float* __restrict__ theta_log,
                      const float* __restrict__ gamma_log,
                      const float* __restrict__ Bre,
                      const float* __restrict__ Bim,
                      const float* __restrict__ Cre,
                      const float* __restrict__ Cim,
                      const float* __restrict__ Dw,
                      float* __restrict__ out)
{
    // x-tile [t][c] bf16, row stride 136 shorts = 272B (single buffer, R2-exact)
    __shared__ short  xs[TC * 136];
    // u/h interleaved [t][n](re,im) bf16 pairs, row stride 132 uints = 528B
    __shared__ uint32 uh[TC * 132];

    const int bid  = blockIdx.x;
    const int ibin = bid >> 2, jj = bid & 3;
    const int bp   = bid >> 7, fp = bid & 127;
    const int tid  = threadIdx.x;
    const int w8   = tid >> 6;          // wave 0..7 -> owns n/h tile w8
    const int lane = tid & 63;
    const int g    = lane >> 4;         // k-group 0..3
    const int c15  = lane & 15;

    // ---- scan params: thread ns = tid&127 owns state chain n=ns (tid<128) ----
    const int ns = tid & 127;
    float lam_re, lam_im;
    {
        float lm = expf(-expf(nu_log[ibin * H_ + ns]));
        float th = expf(theta_log[ibin * H_ + ns]);
        lam_re = lm * cosf(th);
        lam_im = lm * sinf(th);
    }

    // ---- persistent weight fragments: wave w8 owns tile w8 (half of R2's load) ----
    short8 bfr[4], bfi[4];   // B-op matmul1: [kblock]
    short8 cf[8];            // B-op matmul2 (K'=256 interleave): [kblock]
    float  gam, Dh;
    {
        const int ncol = w8 * 16 + c15;          // n (m1) == h (m2) column
        gam = expf(gamma_log[ibin * H_ + ncol]);
        Dh  = Dw[ibin * H_ + ncol];
        const float* br = Bre + ((size_t)ibin * H_ + ncol) * H_;
        const float* bi = Bim + ((size_t)ibin * H_ + ncol) * H_;
        #pragma unroll
        for (int kb = 0; kb < 4; ++kb) {
            const int c0 = kb * 32 + g * 8;      // 8 consecutive c
            f4 r0 = *(const f4*)(br + c0), r1 = *(const f4*)(br + c0 + 4);
            f4 i0 = *(const f4*)(bi + c0), i1 = *(const f4*)(bi + c0 + 4);
            short8 fr, fi;
            #pragma unroll
            for (int u = 0; u < 4; ++u) {
                fr[u]     = (short)f2bf(r0[u]);
                fr[u + 4] = (short)f2bf(r1[u]);
                fi[u]     = (short)f2bf(i0[u]);
                fi[u + 4] = (short)f2bf(i1[u]);
            }
            bfr[kb] = fr; bfi[kb] = fi;
        }
        const float* cr = Cre + ((size_t)ibin * H_ + ncol) * H_;
        const float* ci = Cim + ((size_t)ibin * H_ + ncol) * H_;
        #pragma unroll
        for (int kb = 0; kb < 8; ++kb) {
            const int n0 = kb * 16 + g * 4;      // 4 consecutive n -> 8 interleaved k'
            f4 vr = *(const f4*)(cr + n0);
            f4 vi = *(const f4*)(ci + n0);
            short8 fc;
            #pragma unroll
            for (int u = 0; u < 4; ++u) {
                fc[2 * u]     = (short)f2bf(vr[u]);
                fc[2 * u + 1] = (short)f2bf(-vi[u]);
            }
            cf[kb] = fc;
        }
    }

    float hr = 0.f, hi = 0.f;          // fp32 scan state (threads 0..127)

    const int cstage = tid & 127;       // staging: channel row
    const int tq     = tid >> 7;        // staging: t quarter (0..3)
    const float* xrow = x + (((size_t)bp * H_ + cstage) * F_ + fp) * T_;

    for (int ch = 0; ch < NCH; ++ch) {
        const int t0 = ch * TC;

        // ---- phase A: stage+transpose x chunk -> xs[t][c] bf16 (R2 pattern) ----
        #pragma unroll
        for (int q = 0; q < 4; ++q) {
            const int tl = tq * 16 + q * 4;
            f4 v = *(const f4*)(xrow + t0 + tl);
            xs[(tl + 0) * 136 + cstage] = (short)f2bf(v[0]);
            xs[(tl + 1) * 136 + cstage] = (short)f2bf(v[1]);
            xs[(tl + 2) * 136 + cstage] = (short)f2bf(v[2]);
            xs[(tl + 3) * 136 + cstage] = (short)f2bf(v[3]);
        }
        __syncthreads();   // sync0: x staged

        // ---- phase B: U = X^T * B (wave w8 -> n-tile w8; kb-outer, R2 order) ----
        {
            f32x4 ar[4], ai[4];
            #pragma unroll
            for (int tt = 0; tt < 4; ++tt) { ar[tt] = (f32x4)0.f; ai[tt] = (f32x4)0.f; }

            #pragma unroll
            for (int kb = 0; kb < 4; ++kb) {
                #pragma unroll
                for (int tt = 0; tt < 4; ++tt) {
                    short8 a = *(const short8*)(xs + (tt * 16 + c15) * 136 + kb * 32 + g * 8);
                    ar[tt] = __builtin_amdgcn_mfma_f32_16x16x32_bf16(a, bfr[kb], ar[tt], 0, 0, 0);
                    ai[tt] = __builtin_amdgcn_mfma_f32_16x16x32_bf16(a, bfi[kb], ai[tt], 0, 0, 0);
                }
            }
            // write u = gamma*acc, interleaved bf16 pairs (R2-exact)
            const int n = w8 * 16 + c15;
            #pragma unroll
            for (int tt = 0; tt < 4; ++tt)
                #pragma unroll
                for (int r = 0; r < 4; ++r) {
                    const int t = tt * 16 + g * 4 + r;
                    float ur = gam * ar[tt][r];
                    float ui = gam * ai[tt][r];
                    uh[t * 132 + n] = (uint32)f2bf(ur) | ((uint32)f2bf(ui) << 16);
                }
        }
        __syncthreads();   // sync1: u ready

        // ---- phase C: sequential scan h = lam*h + u (R2-exact, threads 0..127) ----
        if (tid < 128) {
            uint32* col = uh + ns;
            #pragma unroll
            for (int t = 0; t < TC; ++t) {
                uint32 v = col[t * 132];
                float ur = __uint_as_float(v << 16);
                float ui = __uint_as_float(v & 0xffff0000u);
                float nr = fmaf(lam_re, hr, fmaf(-lam_im, hi, ur));
                float ni = fmaf(lam_re, hi, fmaf(lam_im, hr, ui));
                hr = nr; hi = ni;
                col[t * 132] = (uint32)f2bf(hr) | ((uint32)f2bf(hi) << 16);
            }
        }
        __syncthreads();   // sync2: h final

        // ---- phase D: Y = hI * CI (K'=256) + D*x (global fp32, R2-exact) ----
        {
            f32x4 ay[4];
            #pragma unroll
            for (int tt = 0; tt < 4; ++tt) ay[tt] = (f32x4)0.f;

            const short* uhs = (const short*)uh;    // row stride 264 shorts
            #pragma unroll
            for (int kb = 0; kb < 8; ++kb) {
                #pragma unroll
                for (int tt = 0; tt < 4; ++tt) {
                    short8 ah = *(const short8*)(uhs + (tt * 16 + c15) * 264 + kb * 32 + g * 8);
                    ay[tt] = __builtin_amdgcn_mfma_f32_16x16x32_bf16(ah, cf[kb], ay[tt], 0, 0, 0);
                }
            }
            const int h = w8 * 16 + c15;
            #pragma unroll
            for (int tt = 0; tt < 4; ++tt) {
                const int t = t0 + tt * 16 + g * 4;
                f4 xv = *(const f4*)(x + (((size_t)bp * H_ + h) * F_ + fp) * T_ + t);
                f4 y;
                #pragma unroll
                for (int r = 0; r < 4; ++r) y[r] = fmaf(Dh, xv[r], ay[tt][r]);
                *(f4*)(out + (((size_t)jj * H_ + h) * F_ + ibin) * T_ + t) = y;
            }
        }
        __syncthreads();   // sync3: uh/xs reads done before next chunk's writes
    }
}

extern "C" void kernel_launch(void* const* d_in, const int* in_sizes, int n_in,
                              void* d_out, int out_size, void* d_ws, size_t ws_size,
                              hipStream_t stream) {
    (void)in_sizes; (void)n_in; (void)d_ws; (void)ws_size; (void)out_size;
    const float* x         = (const float*)d_in[0];
    const float* nu_log    = (const float*)d_in[1];
    const float* theta_log = (const float*)d_in[2];
    const float* gamma_log = (const float*)d_in[3];
    const float* Bre       = (const float*)d_in[4];
    const float* Bim       = (const float*)d_in[5];
    const float* Cre       = (const float*)d_in[6];
    const float* Cim       = (const float*)d_in[7];
    const float* Dw        = (const float*)d_in[8];
    float* out = (float*)d_out;

    dim3 grid(F_ * B_);   // 512 blocks: one per (i, j)
    dim3 block(512);      // 8 waves: one 16-wide n/h tile per wave
    hipLaunchKernelGGL(lru_mfma7_kernel, grid, block, 0, stream,
                       x, nu_log, theta_log, gamma_log,
                       Bre, Bim, Cre, Cim, Dw, out);
}